// Round 3
// baseline (115.576 us; speedup 1.0000x reference)
//
#include <hip/hip_runtime.h>

// min_m ||pred[b,n]-target[b,m]|| mean over (b,n). B=32, N=M=4096, fp32.
// fp32 VALU-bound (no fp32 MFMA on CDNA4). Floor: 3 FMA + 0.5 min3 per pair
// ~= 3.6 VALU lane-ops/pair -> ~25 us at full VALU issue.
//
// R2 counters: VALUBusy "100%" (gfx94x formula = 2x over-report on SIMD-32,
// true ~50%), Occupancy 28% (4 blocks/CU), kernel A 48.6 us. Stalls: low
// occupancy + unpipelined ds_read->wait->compute loop.
// R3: MS=16 (2048 blocks -> 8 blocks/CU, 4 KB LDS), register double-buffer of
// the 4-target tile, __launch_bounds__(256,8) to keep VGPR<=64. Finish kernel
// is one block with a direct store (drops the out-memset dispatch).

constexpr int Bc = 32;
constexpr int Nc = 4096;
constexpr int Mc = 4096;
constexpr int BLOCK = 256;
constexpr int P = 4;                    // preds per thread
constexpr int MS = 16;                  // target splits per batch
constexpr int TGTS = Mc / MS;           // 256 targets staged per block (4 KB)
constexpr int NCH = Nc / (BLOCK * P);   // 4 pred chunks per batch
// grid A = Bc * NCH * MS = 2048 blocks

static_assert(TGTS == BLOCK, "staging assumes one target per thread");

__global__ __launch_bounds__(BLOCK, 8) void emd_partial_kernel(
    const float* __restrict__ pred, const float* __restrict__ target,
    unsigned int* __restrict__ wmin) {
  __shared__ float4 tgt[TGTS];  // 4 KB

  const int bid = blockIdx.x;
  const int b = bid >> 6;            // / (NCH*MS)
  const int chunk = (bid >> 4) & 3;  // NCH index
  const int ms = bid & 15;           // target-split index

  // Stage + transform targets: (-2tx,-2ty,-2tz,|t|^2). One per thread.
  {
    const float* tb = target + ((size_t)b * Mc + ms * TGTS + threadIdx.x) * 3;
    float tx = tb[0], ty = tb[1], tz = tb[2];
    tgt[threadIdx.x] = make_float4(-2.0f * tx, -2.0f * ty, -2.0f * tz,
                                   fmaf(tx, tx, fmaf(ty, ty, tz * tz)));
  }
  __syncthreads();

  // P=4 pred points per thread, strided by BLOCK for coalesced loads.
  float px[P], py[P], pz[P];
  const int nbase = chunk * (BLOCK * P) + threadIdx.x;
#pragma unroll
  for (int k = 0; k < P; ++k) {
    const float* pb = pred + ((size_t)b * Nc + nbase + k * BLOCK) * 3;
    px[k] = pb[0]; py[k] = pb[1]; pz[k] = pb[2];
  }

  float r0[P], r1[P];
#pragma unroll
  for (int k = 0; k < P; ++k) { r0[k] = 3.4e38f; r1[k] = 3.4e38f; }

  auto body = [&](float4 ta, float4 tb4, float4 tc, float4 td) {
#pragma unroll
    for (int k = 0; k < P; ++k) {
      float da = fmaf(px[k], ta.x, fmaf(py[k], ta.y, fmaf(pz[k], ta.z, ta.w)));
      float db = fmaf(px[k], tb4.x, fmaf(py[k], tb4.y, fmaf(pz[k], tb4.z, tb4.w)));
      float dc = fmaf(px[k], tc.x, fmaf(py[k], tc.y, fmaf(pz[k], tc.z, tc.w)));
      float dd = fmaf(px[k], td.x, fmaf(py[k], td.y, fmaf(pz[k], td.z, td.w)));
      r0[k] = fminf(fminf(da, db), r0[k]);  // v_min3_f32
      r1[k] = fminf(fminf(dc, dd), r1[k]);
    }
  };

  // Register double-buffer: prefetch next 4-target tile while computing current.
  float4 c0 = tgt[0], c1 = tgt[1], c2 = tgt[2], c3 = tgt[3];
#pragma unroll 1
  for (int m = 0; m < TGTS - 4; m += 4) {
    float4 n0 = tgt[m + 4], n1 = tgt[m + 5], n2 = tgt[m + 6], n3 = tgt[m + 7];
    body(c0, c1, c2, c3);
    c0 = n0; c1 = n1; c2 = n2; c3 = n3;
  }
  body(c0, c1, c2, c3);

  // Cross-block min combine: d2 >= 0, so float order == uint order.
#pragma unroll
  for (int k = 0; k < P; ++k) {
    float p2 = fmaf(px[k], px[k], fmaf(py[k], py[k], pz[k] * pz[k]));
    float d2 = fmaxf(fminf(r0[k], r1[k]) + p2, 0.0f);
    atomicMin(&wmin[b * Nc + nbase + k * BLOCK], __float_as_uint(d2));
  }
}

__global__ __launch_bounds__(1024) void emd_finish_kernel(
    const uint4* __restrict__ wmin, float* __restrict__ out) {
  __shared__ float wsum[16];
  float s = 0.0f;
#pragma unroll 4
  for (int i = threadIdx.x; i < Bc * Nc / 4; i += 1024) {
    uint4 v = wmin[i];
    s += sqrtf(__uint_as_float(v.x)) + sqrtf(__uint_as_float(v.y)) +
         sqrtf(__uint_as_float(v.z)) + sqrtf(__uint_as_float(v.w));
  }
#pragma unroll
  for (int off = 32; off > 0; off >>= 1) s += __shfl_down(s, off, 64);
  if ((threadIdx.x & 63) == 0) wsum[threadIdx.x >> 6] = s;
  __syncthreads();
  if (threadIdx.x == 0) {
    float tot = 0.0f;
#pragma unroll
    for (int w = 0; w < 16; ++w) tot += wsum[w];
    out[0] = tot * (1.0f / (float)(Bc * Nc));
  }
}

extern "C" void kernel_launch(void* const* d_in, const int* in_sizes, int n_in,
                              void* d_out, int out_size, void* d_ws, size_t ws_size,
                              hipStream_t stream) {
  const float* pred = (const float*)d_in[0];
  const float* target = (const float*)d_in[1];
  float* out = (float*)d_out;
  unsigned int* wmin = (unsigned int*)d_ws;  // Bc*Nc uints = 512 KB

  // 0xFFFFFFFF acts as +inf for unsigned atomicMin.
  hipMemsetAsync(wmin, 0xFF, (size_t)Bc * Nc * sizeof(unsigned int), stream);

  emd_partial_kernel<<<dim3(Bc * NCH * MS), dim3(BLOCK), 0, stream>>>(pred, target, wmin);
  emd_finish_kernel<<<dim3(1), dim3(1024), 0, stream>>>((const uint4*)wmin, out);
}

// Round 4
// 113.502 us; speedup vs baseline: 1.0183x; 1.0183x over previous
//
#include <hip/hip_runtime.h>

// min_m ||pred[b,n]-target[b,m]|| mean over (b,n). B=32, N=M=4096, fp32.
// fp32 VALU-bound (no fp32 MFMA on CDNA4). Floor: 3 FMA + 0.5 min3 per pair
// = 3.5 VALU lane-ops/pair -> ~29 us at ~2.0 GHz sustained clock.
//
// R3 lesson: explicit register double-buffer on an unroll-1 loop forced ~16
// v_mov/iter (compiler can't rename across iterations) -> regressed. The
// compiler's own batched ds_read_b128 + incremental lgkmcnt already pipelines.
// R4: P=8 preds/thread, 8-target tile, no manual prefetch. DS:VALU = 1:28,
// 16 independent min3 chains for ILP.

constexpr int Bc = 32;
constexpr int Nc = 4096;
constexpr int Mc = 4096;
constexpr int BLOCK = 256;
constexpr int P = 8;                    // preds per thread
constexpr int MS = 16;                  // target splits per batch
constexpr int TGTS = Mc / MS;           // 256 targets staged per block (4 KB)
constexpr int NCH = Nc / (BLOCK * P);   // 2 pred chunks per batch
// grid A = Bc * NCH * MS = 1024 blocks -> 4 blocks/CU, 16 waves/CU

static_assert(TGTS == BLOCK, "staging assumes one target per thread");

__global__ __launch_bounds__(BLOCK, 4) void emd_partial_kernel(
    const float* __restrict__ pred, const float* __restrict__ target,
    unsigned int* __restrict__ wmin) {
  __shared__ float4 tgt[TGTS];  // 4 KB

  const int bid = blockIdx.x;
  const int b = bid >> 5;            // / (NCH*MS)
  const int chunk = (bid >> 4) & 1;  // NCH index
  const int ms = bid & 15;           // target-split index

  // Stage + transform targets: (-2tx,-2ty,-2tz,|t|^2). One per thread.
  {
    const float* tb = target + ((size_t)b * Mc + ms * TGTS + threadIdx.x) * 3;
    float tx = tb[0], ty = tb[1], tz = tb[2];
    tgt[threadIdx.x] = make_float4(-2.0f * tx, -2.0f * ty, -2.0f * tz,
                                   fmaf(tx, tx, fmaf(ty, ty, tz * tz)));
  }
  __syncthreads();

  // P=8 pred points per thread, strided by BLOCK for coalesced loads.
  float px[P], py[P], pz[P];
  const int nbase = chunk * (BLOCK * P) + threadIdx.x;
#pragma unroll
  for (int k = 0; k < P; ++k) {
    const float* pb = pred + ((size_t)b * Nc + nbase + k * BLOCK) * 3;
    px[k] = pb[0]; py[k] = pb[1]; pz[k] = pb[2];
  }

  float r0[P], r1[P];
#pragma unroll
  for (int k = 0; k < P; ++k) { r0[k] = 3.4e38f; r1[k] = 3.4e38f; }

  // 8-target tile per iteration: 8 ds_read_b128 (compiler pipelines via
  // incremental lgkmcnt), then 64 pairs = 192 FMA + 32 min3.
#pragma unroll 1
  for (int m = 0; m < TGTS; m += 8) {
    float4 t0 = tgt[m + 0];
    float4 t1 = tgt[m + 1];
    float4 t2 = tgt[m + 2];
    float4 t3 = tgt[m + 3];
    float4 t4 = tgt[m + 4];
    float4 t5 = tgt[m + 5];
    float4 t6 = tgt[m + 6];
    float4 t7 = tgt[m + 7];
#pragma unroll
    for (int k = 0; k < P; ++k) {
      float d0 = fmaf(px[k], t0.x, fmaf(py[k], t0.y, fmaf(pz[k], t0.z, t0.w)));
      float d1 = fmaf(px[k], t1.x, fmaf(py[k], t1.y, fmaf(pz[k], t1.z, t1.w)));
      float d2 = fmaf(px[k], t2.x, fmaf(py[k], t2.y, fmaf(pz[k], t2.z, t2.w)));
      float d3 = fmaf(px[k], t3.x, fmaf(py[k], t3.y, fmaf(pz[k], t3.z, t3.w)));
      float d4 = fmaf(px[k], t4.x, fmaf(py[k], t4.y, fmaf(pz[k], t4.z, t4.w)));
      float d5 = fmaf(px[k], t5.x, fmaf(py[k], t5.y, fmaf(pz[k], t5.z, t5.w)));
      float d6 = fmaf(px[k], t6.x, fmaf(py[k], t6.y, fmaf(pz[k], t6.z, t6.w)));
      float d7 = fmaf(px[k], t7.x, fmaf(py[k], t7.y, fmaf(pz[k], t7.z, t7.w)));
      r0[k] = fminf(fminf(d0, d1), r0[k]);  // v_min3_f32
      r1[k] = fminf(fminf(d2, d3), r1[k]);
      r0[k] = fminf(fminf(d4, d5), r0[k]);
      r1[k] = fminf(fminf(d6, d7), r1[k]);
    }
  }

  // Cross-block min combine: d2 >= 0, so float order == uint order.
#pragma unroll
  for (int k = 0; k < P; ++k) {
    float p2 = fmaf(px[k], px[k], fmaf(py[k], py[k], pz[k] * pz[k]));
    float d2 = fmaxf(fminf(r0[k], r1[k]) + p2, 0.0f);
    atomicMin(&wmin[b * Nc + nbase + k * BLOCK], __float_as_uint(d2));
  }
}

__global__ __launch_bounds__(1024) void emd_finish_kernel(
    const uint4* __restrict__ wmin, float* __restrict__ out) {
  __shared__ float wsum[16];
  // 32768 uint4 over 1024 threads = 32 each; 4 independent accumulators.
  float s0 = 0.0f, s1 = 0.0f, s2 = 0.0f, s3 = 0.0f;
#pragma unroll 4
  for (int i = threadIdx.x; i < Bc * Nc / 4; i += 1024) {
    uint4 v = wmin[i];
    s0 += sqrtf(__uint_as_float(v.x));
    s1 += sqrtf(__uint_as_float(v.y));
    s2 += sqrtf(__uint_as_float(v.z));
    s3 += sqrtf(__uint_as_float(v.w));
  }
  float s = (s0 + s1) + (s2 + s3);
#pragma unroll
  for (int off = 32; off > 0; off >>= 1) s += __shfl_down(s, off, 64);
  if ((threadIdx.x & 63) == 0) wsum[threadIdx.x >> 6] = s;
  __syncthreads();
  if (threadIdx.x == 0) {
    float tot = 0.0f;
#pragma unroll
    for (int w = 0; w < 16; ++w) tot += wsum[w];
    out[0] = tot * (1.0f / (float)(Bc * Nc));
  }
}

extern "C" void kernel_launch(void* const* d_in, const int* in_sizes, int n_in,
                              void* d_out, int out_size, void* d_ws, size_t ws_size,
                              hipStream_t stream) {
  const float* pred = (const float*)d_in[0];
  const float* target = (const float*)d_in[1];
  float* out = (float*)d_out;
  unsigned int* wmin = (unsigned int*)d_ws;  // Bc*Nc uints = 512 KB

  // 0xFFFFFFFF acts as +inf for unsigned atomicMin.
  hipMemsetAsync(wmin, 0xFF, (size_t)Bc * Nc * sizeof(unsigned int), stream);

  emd_partial_kernel<<<dim3(Bc * NCH * MS), dim3(BLOCK), 0, stream>>>(pred, target, wmin);
  emd_finish_kernel<<<dim3(1), dim3(1024), 0, stream>>>((const uint4*)wmin, out);
}